// Round 11
// baseline (2654.266 us; speedup 1.0000x reference)
//
#include <hip/hip_runtime.h>

// Round 11: R5/R8 fp32 scaffold, ONE change: OUTPUT IS FLOAT32 (not bf16).
// R10 diagnostic: a ushort write to out[0] was invisible (denormal in a float32
// word) -> output buffer is fp32. The "(bf16" in the assert label is a
// hardcoded f-string, not a dtype report. All prior ~6.19 errors were my bf16
// pairs misread as packed float32 words (position misalignment), not math bugs.
// Established: gimage fp32, pts int32, weights fp32 (probe bisection R3-R8).

typedef __attribute__((ext_vector_type(4))) float f32x4;

#define LS 260  // LDS row stride (floats)

__device__ __forceinline__ float sigm(float y) { return 1.f / (1.f + __expf(-y)); }

// ---- GroupNorm(32 groups x 8 ch) + affine + SiLU, fp32 LDS -> fp32 LDS ----
__device__ __forceinline__ void gn_silu(const float* __restrict__ src,
                                        float* __restrict__ dst,
                                        const float* __restrict__ gw,
                                        const float* __restrict__ gb, int t) {
  #pragma unroll
  for (int i = 0; i < 4; i++) {
    int task = (i << 8) + t;       // 1024 tasks = 32 rows x 32 groups
    int r = task >> 5, g = task & 31;
    const float* x = src + r * LS + (g << 3);
    f32x4 x0 = *(const f32x4*)x, x1 = *(const f32x4*)(x + 4);
    float xx[8] = {x0[0], x0[1], x0[2], x0[3], x1[0], x1[1], x1[2], x1[3]};
    float s = 0.f, q = 0.f;
    #pragma unroll
    for (int j = 0; j < 8; j++) { s += xx[j]; q += xx[j] * xx[j]; }
    float mu = s * 0.125f;
    float rs = rsqrtf(q * 0.125f - mu * mu + 1e-5f);
    const float* w = gw + (g << 3);
    const float* b = gb + (g << 3);
    float* d = dst + r * LS + (g << 3);
    #pragma unroll
    for (int j = 0; j < 8; j++) {
      float y = (xx[j] - mu) * rs * w[j] + b[j];
      d[j] = y * sigm(y);
    }
  }
}

// ---- fp32 GEMM: 32 rows x 256 cols, K=256. Thread t owns column n=t.
// CONV: W is conv [n][k][3][3] fp32, center tap (stride 9). else dense [n][k].
// EPI: 0 -> dst = acc+bias ; 1 -> X += acc+bias (residual) ; 2 -> dst = relu(acc+bias)
template <int EPI, bool CONV>
__device__ __forceinline__ void gemm_f32(const float* __restrict__ src,
                                         const float* __restrict__ W,
                                         const float* __restrict__ bias,
                                         float* __restrict__ dst,
                                         float* __restrict__ X) {
  const int n = threadIdx.x;
  float acc[32];
  #pragma unroll
  for (int r = 0; r < 32; r++) acc[r] = 0.f;

  #pragma unroll 1
  for (int k = 0; k < 256; k += 8) {
    float w[8];
    if (CONV) {
      #pragma unroll
      for (int j = 0; j < 8; j++)
        w[j] = W[(size_t)((n << 8) + k + j) * 9 + 4];
    } else {
      f32x4 wa = *(const f32x4*)(W + (n << 8) + k);
      f32x4 wb = *(const f32x4*)(W + (n << 8) + k + 4);
      w[0] = wa[0]; w[1] = wa[1]; w[2] = wa[2]; w[3] = wa[3];
      w[4] = wb[0]; w[5] = wb[1]; w[6] = wb[2]; w[7] = wb[3];
    }
    #pragma unroll
    for (int r = 0; r < 32; r++) {
      const float* xr = src + r * LS + k;      // same addr across lanes -> LDS broadcast
      f32x4 a0 = *(const f32x4*)xr, a1 = *(const f32x4*)(xr + 4);
      acc[r] += a0[0] * w[0] + a0[1] * w[1] + a0[2] * w[2] + a0[3] * w[3]
              + a1[0] * w[4] + a1[1] * w[5] + a1[2] * w[6] + a1[3] * w[7];
    }
  }

  float bv = bias[n];
  #pragma unroll
  for (int r = 0; r < 32; r++) {
    float v = acc[r] + bv;
    if (EPI == 0) dst[r * LS + n] = v;
    else if (EPI == 1) X[r * LS + n] += v;
    else dst[r * LS + n] = fmaxf(v, 0.f);
  }
}

__global__ __launch_bounds__(256, 1) void fused_all(
    const float* __restrict__ gimage, const int* __restrict__ pts,
    const float* __restrict__ gn1w, const float* __restrict__ gn1b,
    const float* __restrict__ c1w, const float* __restrict__ c1b,
    const float* __restrict__ gn2w, const float* __restrict__ gn2b,
    const float* __restrict__ c2w, const float* __restrict__ c2b,
    const float* __restrict__ clsw, const float* __restrict__ clsb,
    const float* __restrict__ w1, const float* __restrict__ b1,
    const float* __restrict__ w2, const float* __restrict__ b2,
    const float* __restrict__ w3, const float* __restrict__ b3,
    float* __restrict__ out) {
  __shared__ float X[32 * LS];   // residual stream
  __shared__ float A[32 * LS];   // activation
  __shared__ float H[32 * LS];   // hidden

  const int t = threadIdx.x;
  const int row0 = blockIdx.x << 5;   // 32 rows per block

  // ---- gather: X[r, :] = gimage[b, :, lin_r] ----
  {
    int r = t >> 3;              // 0..31
    int c0 = (t & 7) << 5;       // channel slab of 32
    int grow = row0 + r;
    int p0 = pts[2 * grow], p1 = pts[2 * grow + 1];
    int lin = ((p0 >> 3) << 5) + (p1 >> 3);   // idx0*W + idx1 (reference formula)
    int b = grow >> 11;          // 2048 candidates per batch
    const float* src = gimage + (((size_t)((b << 8) + c0)) << 10) + lin;
    #pragma unroll
    for (int c = 0; c < 32; c++)
      X[r * LS + c0 + c] = src[(size_t)c << 10];
  }
  __syncthreads();

  // ---- 2x ResBlock: GN->SiLU->conv1(center) -> GN->SiLU->conv2(center) -> +skip ----
  #pragma unroll 1
  for (int rb = 0; rb < 2; rb++) {
    gn_silu(X, A, gn1w + (rb << 8), gn1b + (rb << 8), t);
    __syncthreads();
    gemm_f32<0, true>(A, c1w + rb * 589824, c1b + (rb << 8), H, nullptr);
    __syncthreads();
    gn_silu(H, A, gn2w + (rb << 8), gn2b + (rb << 8), t);
    __syncthreads();
    gemm_f32<1, true>(A, c2w + rb * 589824, c2b + (rb << 8), nullptr, X);
    __syncthreads();
  }

  // ---- logits head: x @ cls_w.T + cls_b  -> out[0 : 131072] (fp32) ----
  if (t < 64) {
    int r = t >> 1, j = t & 1;
    float s = clsb[j];
    const float* w = clsw + (j << 8);
    const float* x = X + r * LS;
    #pragma unroll 1
    for (int k = 0; k < 256; k += 4) {
      f32x4 wv = *(const f32x4*)(w + k);
      f32x4 xv = *(const f32x4*)(x + k);
      s += xv[0] * wv[0] + xv[1] * wv[1] + xv[2] * wv[2] + xv[3] * wv[3];
    }
    out[((size_t)(row0 + r) << 1) + j] = s;
  }
  // (no barrier needed: head reads X; next gemm reads X, writes H — no conflict)

  // ---- MLP box head: relu(x@w1.T+b1) -> relu(.@w2.T+b2) -> sigmoid(.@w3.T+b3) ----
  gemm_f32<2, false>(X, w1, b1, H, nullptr);
  __syncthreads();
  gemm_f32<2, false>(H, w2, b2, A, nullptr);
  __syncthreads();
  if (t < 128) {
    int r = t >> 2, j = t & 3;
    float s = b3[j];
    const float* w = w3 + (j << 8);
    const float* x = A + r * LS;
    #pragma unroll 1
    for (int k = 0; k < 256; k += 4) {
      f32x4 wv = *(const f32x4*)(w + k);
      f32x4 xv = *(const f32x4*)(x + k);
      s += xv[0] * wv[0] + xv[1] * wv[1] + xv[2] * wv[2] + xv[3] * wv[3];
    }
    out[131072 + ((size_t)(row0 + r) << 2) + j] = sigm(s);
  }
}

extern "C" void kernel_launch(void* const* d_in, const int* in_sizes, int n_in,
                              void* d_out, int out_size, void* d_ws, size_t ws_size,
                              hipStream_t stream) {
  const float* gimage = (const float*)d_in[0];
  const int* pts = (const int*)d_in[1];
  const float* gn1w = (const float*)d_in[2];
  const float* gn1b = (const float*)d_in[3];
  const float* c1w = (const float*)d_in[4];
  const float* c1b = (const float*)d_in[5];
  const float* gn2w = (const float*)d_in[6];
  const float* gn2b = (const float*)d_in[7];
  const float* c2w = (const float*)d_in[8];
  const float* c2b = (const float*)d_in[9];
  const float* clsw = (const float*)d_in[10];
  const float* clsb = (const float*)d_in[11];
  const float* w1 = (const float*)d_in[12];
  const float* b1 = (const float*)d_in[13];
  const float* w2 = (const float*)d_in[14];
  const float* b2 = (const float*)d_in[15];
  const float* w3 = (const float*)d_in[16];
  const float* b3 = (const float*)d_in[17];

  fused_all<<<2048, 256, 0, stream>>>(gimage, pts, gn1w, gn1b, c1w, c1b,
                                      gn2w, gn2b, c2w, c2b, clsw, clsb,
                                      w1, b1, w2, b2, w3, b3,
                                      (float*)d_out);
}

// Round 14
// 774.739 us; speedup vs baseline: 3.4260x; 3.4260x over previous
//
#include <hip/hip_runtime.h>

// Round 14: split-precision fp16 MFMA (hi+lo operand pairs, 3 MFMA products).
// R12(bf16)=0.252 / R13(fp16)=0.281 -> error is operand-precision-INDEPENDENT.
// This round: effective ~22-bit mantissa operands (fp32-equivalent numerics)
// with the SAME kernel structure. PASS => noise theory dead + MFMA validated
// (ship the speedup). FAIL ~0.25 => structural bug proven; bisect MFMA->VALU.
// fp32 fallback (R11, proven, 2654us) retained for ws_size < 1.57 MB.

typedef __attribute__((ext_vector_type(8))) _Float16 half8;
typedef __attribute__((ext_vector_type(4))) float f32x4;

#define XS 260   // fp32 X stride
#define AS 264   // fp16 A stride (+8 pad)

#define NHALF  393216    // elements per precision plane in ws
#define OFF_WC1 0        // [2][256][256]
#define OFF_WC2 131072
#define OFF_W1  262144   // [256][256]
#define OFF_W2  327680
#define WS_NEED 1572864  // bytes = 2 planes x 393216 halves x 2B

__device__ __forceinline__ float sigm(float y) { return 1.f / (1.f + __expf(-y)); }

// ---- prep: pack weights as fp16 hi/lo planes: wsl = wsh + NHALF ----
__global__ __launch_bounds__(256) void prep(const float* __restrict__ c1w,
                                            const float* __restrict__ c2w,
                                            const float* __restrict__ w1,
                                            const float* __restrict__ w2,
                                            _Float16* __restrict__ ws) {
  int i = blockIdx.x * 256 + threadIdx.x;  // 0..131071
  {
    float v = c1w[(size_t)i * 9 + 4];
    _Float16 h = (_Float16)v;
    ws[OFF_WC1 + i] = h;
    ws[NHALF + OFF_WC1 + i] = (_Float16)(v - (float)h);
  }
  {
    float v = c2w[(size_t)i * 9 + 4];
    _Float16 h = (_Float16)v;
    ws[OFF_WC2 + i] = h;
    ws[NHALF + OFF_WC2 + i] = (_Float16)(v - (float)h);
  }
  if (i < 65536) {
    float v = w1[i];
    _Float16 h = (_Float16)v;
    ws[OFF_W1 + i] = h;
    ws[NHALF + OFF_W1 + i] = (_Float16)(v - (float)h);
    v = w2[i];
    h = (_Float16)v;
    ws[OFF_W2 + i] = h;
    ws[NHALF + OFF_W2 + i] = (_Float16)(v - (float)h);
  }
}

// ---- GN(32x8)+SiLU: fp32 X -> fp16 hi/lo A ----
__device__ __forceinline__ void gn_silu_f(const float* __restrict__ X,
                                          _Float16* Ah, _Float16* Al,
                                          const float* __restrict__ gw,
                                          const float* __restrict__ gb, int t) {
  #pragma unroll
  for (int i = 0; i < 4; i++) {
    int task = (i << 8) + t;   // 1024 = 32 rows x 32 groups
    int r = task >> 5, g = task & 31;
    const float* x = X + r * XS + (g << 3);
    f32x4 x0 = *(const f32x4*)x, x1 = *(const f32x4*)(x + 4);
    float xx[8] = {x0[0], x0[1], x0[2], x0[3], x1[0], x1[1], x1[2], x1[3]};
    float s = 0.f, q = 0.f;
    #pragma unroll
    for (int j = 0; j < 8; j++) { s += xx[j]; q += xx[j] * xx[j]; }
    float mu = s * 0.125f;
    float rs = rsqrtf(q * 0.125f - mu * mu + 1e-5f);
    const float* w = gw + (g << 3);
    const float* b = gb + (g << 3);
    half8 oh, ol;
    #pragma unroll
    for (int j = 0; j < 8; j++) {
      float y = (xx[j] - mu) * rs * w[j] + b[j];
      float sv = y * sigm(y);
      _Float16 h = (_Float16)sv;
      oh[j] = h;
      ol[j] = (_Float16)(sv - (float)h);
    }
    *(half8*)(Ah + r * AS + (g << 3)) = oh;
    *(half8*)(Al + r * AS + (g << 3)) = ol;
  }
}

// ---- GN(32x8)+SiLU in-place on hi/lo A ----
__device__ __forceinline__ void gn_silu_h(_Float16* Ah, _Float16* Al,
                                          const float* __restrict__ gw,
                                          const float* __restrict__ gb, int t) {
  #pragma unroll
  for (int i = 0; i < 4; i++) {
    int task = (i << 8) + t;
    int r = task >> 5, g = task & 31;
    half8 xh = *(const half8*)(Ah + r * AS + (g << 3));
    half8 xl = *(const half8*)(Al + r * AS + (g << 3));
    float xx[8];
    float s = 0.f, q = 0.f;
    #pragma unroll
    for (int j = 0; j < 8; j++) {
      xx[j] = (float)xh[j] + (float)xl[j];
      s += xx[j]; q += xx[j] * xx[j];
    }
    float mu = s * 0.125f;
    float rs = rsqrtf(q * 0.125f - mu * mu + 1e-5f);
    const float* w = gw + (g << 3);
    const float* b = gb + (g << 3);
    half8 oh, ol;
    #pragma unroll
    for (int j = 0; j < 8; j++) {
      float y = (xx[j] - mu) * rs * w[j] + b[j];
      float sv = y * sigm(y);
      _Float16 h = (_Float16)sv;
      oh[j] = h;
      ol[j] = (_Float16)(sv - (float)h);
    }
    *(half8*)(Ah + r * AS + (g << 3)) = oh;
    *(half8*)(Al + r * AS + (g << 3)) = ol;
  }
}

// ---- 32x256 @ 256x256 split-fp16 MFMA GEMM, in-place on A (hi/lo).
// acc = Ahi*Whi + Ahi*Wlo + Alo*Whi  (fp32 accum; lo*lo dropped, ~2^-22)
// EPI 0: A = hl(acc+bias)            (conv1 -> h)
// EPI 1: X += acc+bias; A = hl(X)    (conv2 -> residual)
// EPI 2: A = hl(relu(acc+bias))      (mlp)
template <int EPI>
__device__ __forceinline__ void gemm32(_Float16* Ah, _Float16* Al,
                                       const _Float16* __restrict__ Wh,
                                       const _Float16* __restrict__ Wl,
                                       const float* __restrict__ bias,
                                       float* X) {
  const int t = threadIdx.x;
  const int lane = t & 63;
  const int col = lane & 15;
  const int quad = lane >> 4;
  const int nb = (t >> 6) << 6;   // wave's 64-col slab

  f32x4 acc[2][4];
  #pragma unroll
  for (int mt = 0; mt < 2; mt++)
    #pragma unroll
    for (int nt = 0; nt < 4; nt++)
      acc[mt][nt] = (f32x4){0.f, 0.f, 0.f, 0.f};

  const int aoff = col * AS + quad * 8;
  const size_t boff = (((size_t)(nb + col)) << 8) + quad * 8;

  #pragma unroll
  for (int kt = 0; kt < 8; kt++) {
    half8 ah[2], al[2], bh[4], bl[4];
    #pragma unroll
    for (int mt = 0; mt < 2; mt++) {
      ah[mt] = *(const half8*)(Ah + aoff + mt * 16 * AS + kt * 32);
      al[mt] = *(const half8*)(Al + aoff + mt * 16 * AS + kt * 32);
    }
    #pragma unroll
    for (int nt = 0; nt < 4; nt++) {
      bh[nt] = *(const half8*)(Wh + boff + (nt << 12) + kt * 32);
      bl[nt] = *(const half8*)(Wl + boff + (nt << 12) + kt * 32);
    }
    #pragma unroll
    for (int mt = 0; mt < 2; mt++)
      #pragma unroll
      for (int nt = 0; nt < 4; nt++)
        acc[mt][nt] = __builtin_amdgcn_mfma_f32_16x16x32_f16(ah[mt], bh[nt], acc[mt][nt], 0, 0, 0);
    #pragma unroll
    for (int mt = 0; mt < 2; mt++)
      #pragma unroll
      for (int nt = 0; nt < 4; nt++)
        acc[mt][nt] = __builtin_amdgcn_mfma_f32_16x16x32_f16(ah[mt], bl[nt], acc[mt][nt], 0, 0, 0);
    #pragma unroll
    for (int mt = 0; mt < 2; mt++)
      #pragma unroll
      for (int nt = 0; nt < 4; nt++)
        acc[mt][nt] = __builtin_amdgcn_mfma_f32_16x16x32_f16(al[mt], bh[nt], acc[mt][nt], 0, 0, 0);
  }

  __syncthreads();  // all frag reads done before in-place epilogue writes

  #pragma unroll
  for (int nt = 0; nt < 4; nt++) {
    int n = nb + (nt << 4) + col;
    float bv = bias[n];
    #pragma unroll
    for (int mt = 0; mt < 2; mt++) {
      #pragma unroll
      for (int rg = 0; rg < 4; rg++) {
        int r = (mt << 4) + (quad << 2) + rg;   // C/D: col=lane&15, row=quad*4+reg
        float v = acc[mt][nt][rg] + bv;
        if (EPI == 1) {
          float xn = X[r * XS + n] + v;
          X[r * XS + n] = xn;
          v = xn;
        } else if (EPI == 2) {
          v = fmaxf(v, 0.f);
        }
        _Float16 h = (_Float16)v;
        Ah[r * AS + n] = h;
        Al[r * AS + n] = (_Float16)(v - (float)h);
      }
    }
  }
}

__global__ __launch_bounds__(256) void fused_mfma(
    const float* __restrict__ gimage, const int* __restrict__ pts,
    const float* __restrict__ gn1w, const float* __restrict__ gn1b,
    const float* __restrict__ c1b,
    const float* __restrict__ gn2w, const float* __restrict__ gn2b,
    const float* __restrict__ c2b,
    const float* __restrict__ clsw, const float* __restrict__ clsb,
    const float* __restrict__ b1, const float* __restrict__ b2,
    const float* __restrict__ w3, const float* __restrict__ b3,
    const _Float16* __restrict__ ws, float* __restrict__ out) {
  __shared__ float X[32 * XS];        // residual, fp32
  __shared__ _Float16 Ah[32 * AS];    // activation hi
  __shared__ _Float16 Al[32 * AS];    // activation lo

  const int t = threadIdx.x;
  const int row0 = blockIdx.x << 5;
  const _Float16* wsl = ws + NHALF;

  // ---- gather: X[r,:] = gimage[b,:,lin_r] ----
  {
    int r = t >> 3;
    int c0 = (t & 7) << 5;
    int grow = row0 + r;
    int p0 = pts[2 * grow], p1 = pts[2 * grow + 1];
    int lin = ((p0 >> 3) << 5) + (p1 >> 3);
    int b = grow >> 11;
    const float* src = gimage + (((size_t)((b << 8) + c0)) << 10) + lin;
    #pragma unroll
    for (int c = 0; c < 32; c++)
      X[r * XS + c0 + c] = src[(size_t)c << 10];
  }
  __syncthreads();

  // ---- 2x ResBlock ----
  #pragma unroll 1
  for (int rb = 0; rb < 2; rb++) {
    gn_silu_f(X, Ah, Al, gn1w + (rb << 8), gn1b + (rb << 8), t);
    __syncthreads();
    gemm32<0>(Ah, Al, ws + OFF_WC1 + rb * 65536, wsl + OFF_WC1 + rb * 65536,
              c1b + (rb << 8), nullptr);
    __syncthreads();
    gn_silu_h(Ah, Al, gn2w + (rb << 8), gn2b + (rb << 8), t);
    __syncthreads();
    gemm32<1>(Ah, Al, ws + OFF_WC2 + rb * 65536, wsl + OFF_WC2 + rb * 65536,
              c2b + (rb << 8), X);
    __syncthreads();
  }

  // ---- logits head (fp32 X) ----
  if (t < 64) {
    int r = t >> 1, j = t & 1;
    float s = clsb[j];
    const float* w = clsw + (j << 8);
    const float* x = X + r * XS;
    #pragma unroll 1
    for (int k = 0; k < 256; k += 4) {
      f32x4 wv = *(const f32x4*)(w + k);
      f32x4 xv = *(const f32x4*)(x + k);
      s += xv[0] * wv[0] + xv[1] * wv[1] + xv[2] * wv[2] + xv[3] * wv[3];
    }
    out[((size_t)(row0 + r) << 1) + j] = s;
  }

  // ---- MLP box head: A holds hl(x) ----
  gemm32<2>(Ah, Al, ws + OFF_W1, wsl + OFF_W1, b1, nullptr);
  __syncthreads();
  gemm32<2>(Ah, Al, ws + OFF_W2, wsl + OFF_W2, b2, nullptr);
  __syncthreads();
  {
    int r = t >> 3, j = t & 7;            // 32 rows x 8 (4 used)
    if (j < 4) {
      float s = b3[j];
      const float* w = w3 + (j << 8);
      const _Float16* xh = Ah + r * AS;
      const _Float16* xl = Al + r * AS;
      #pragma unroll 1
      for (int k = 0; k < 256; k += 4) {
        f32x4 wv = *(const f32x4*)(w + k);
        #pragma unroll
        for (int u = 0; u < 4; u++)
          s += ((float)xh[k + u] + (float)xl[k + u]) * wv[u];
      }
      out[131072 + ((size_t)(row0 + r) << 2) + j] = sigm(s);
    }
  }
}

// ================= fp32 fallback (R11, proven) for tiny ws =================
#define LS 260
template <int EPI, bool CONV>
__device__ __forceinline__ void gemm_f32(const float* __restrict__ src,
                                         const float* __restrict__ W,
                                         const float* __restrict__ bias,
                                         float* __restrict__ dst,
                                         float* __restrict__ X) {
  const int n = threadIdx.x;
  float acc[32];
  #pragma unroll
  for (int r = 0; r < 32; r++) acc[r] = 0.f;
  #pragma unroll 1
  for (int k = 0; k < 256; k += 8) {
    float w[8];
    if (CONV) {
      #pragma unroll
      for (int j = 0; j < 8; j++) w[j] = W[(size_t)((n << 8) + k + j) * 9 + 4];
    } else {
      f32x4 wa = *(const f32x4*)(W + (n << 8) + k);
      f32x4 wb = *(const f32x4*)(W + (n << 8) + k + 4);
      w[0] = wa[0]; w[1] = wa[1]; w[2] = wa[2]; w[3] = wa[3];
      w[4] = wb[0]; w[5] = wb[1]; w[6] = wb[2]; w[7] = wb[3];
    }
    #pragma unroll
    for (int r = 0; r < 32; r++) {
      const float* xr = src + r * LS + k;
      f32x4 a0 = *(const f32x4*)xr, a1 = *(const f32x4*)(xr + 4);
      acc[r] += a0[0] * w[0] + a0[1] * w[1] + a0[2] * w[2] + a0[3] * w[3]
              + a1[0] * w[4] + a1[1] * w[5] + a1[2] * w[6] + a1[3] * w[7];
    }
  }
  float bv = bias[n];
  #pragma unroll
  for (int r = 0; r < 32; r++) {
    float v = acc[r] + bv;
    if (EPI == 0) dst[r * LS + n] = v;
    else if (EPI == 1) X[r * LS + n] += v;
    else dst[r * LS + n] = fmaxf(v, 0.f);
  }
}
__device__ __forceinline__ void gn_silu32(const float* __restrict__ src,
                                          float* __restrict__ dst,
                                          const float* __restrict__ gw,
                                          const float* __restrict__ gb, int t) {
  #pragma unroll
  for (int i = 0; i < 4; i++) {
    int task = (i << 8) + t;
    int r = task >> 5, g = task & 31;
    const float* x = src + r * LS + (g << 3);
    f32x4 x0 = *(const f32x4*)x, x1 = *(const f32x4*)(x + 4);
    float xx[8] = {x0[0], x0[1], x0[2], x0[3], x1[0], x1[1], x1[2], x1[3]};
    float s = 0.f, q = 0.f;
    #pragma unroll
    for (int j = 0; j < 8; j++) { s += xx[j]; q += xx[j] * xx[j]; }
    float mu = s * 0.125f;
    float rs = rsqrtf(q * 0.125f - mu * mu + 1e-5f);
    const float* w = gw + (g << 3);
    const float* b = gb + (g << 3);
    float* d = dst + r * LS + (g << 3);
    #pragma unroll
    for (int j = 0; j < 8; j++) {
      float y = (xx[j] - mu) * rs * w[j] + b[j];
      d[j] = y * sigm(y);
    }
  }
}
__global__ __launch_bounds__(256, 1) void fused_all(
    const float* __restrict__ gimage, const int* __restrict__ pts,
    const float* __restrict__ gn1w, const float* __restrict__ gn1b,
    const float* __restrict__ c1w, const float* __restrict__ c1b,
    const float* __restrict__ gn2w, const float* __restrict__ gn2b,
    const float* __restrict__ c2w, const float* __restrict__ c2b,
    const float* __restrict__ clsw, const float* __restrict__ clsb,
    const float* __restrict__ w1, const float* __restrict__ b1,
    const float* __restrict__ w2, const float* __restrict__ b2,
    const float* __restrict__ w3, const float* __restrict__ b3,
    float* __restrict__ out) {
  __shared__ float X[32 * LS];
  __shared__ float A[32 * LS];
  __shared__ float H[32 * LS];
  const int t = threadIdx.x;
  const int row0 = blockIdx.x << 5;
  {
    int r = t >> 3;
    int c0 = (t & 7) << 5;
    int grow = row0 + r;
    int p0 = pts[2 * grow], p1 = pts[2 * grow + 1];
    int lin = ((p0 >> 3) << 5) + (p1 >> 3);
    int b = grow >> 11;
    const float* src = gimage + (((size_t)((b << 8) + c0)) << 10) + lin;
    #pragma unroll
    for (int c = 0; c < 32; c++) X[r * LS + c0 + c] = src[(size_t)c << 10];
  }
  __syncthreads();
  #pragma unroll 1
  for (int rb = 0; rb < 2; rb++) {
    gn_silu32(X, A, gn1w + (rb << 8), gn1b + (rb << 8), t);
    __syncthreads();
    gemm_f32<0, true>(A, c1w + rb * 589824, c1b + (rb << 8), H, nullptr);
    __syncthreads();
    gn_silu32(H, A, gn2w + (rb << 8), gn2b + (rb << 8), t);
    __syncthreads();
    gemm_f32<1, true>(A, c2w + rb * 589824, c2b + (rb << 8), nullptr, X);
    __syncthreads();
  }
  if (t < 64) {
    int r = t >> 1, j = t & 1;
    float s = clsb[j];
    const float* w = clsw + (j << 8);
    const float* x = X + r * LS;
    #pragma unroll 1
    for (int k = 0; k < 256; k += 4) {
      f32x4 wv = *(const f32x4*)(w + k);
      f32x4 xv = *(const f32x4*)(x + k);
      s += xv[0] * wv[0] + xv[1] * wv[1] + xv[2] * wv[2] + xv[3] * wv[3];
    }
    out[((size_t)(row0 + r) << 1) + j] = s;
  }
  gemm_f32<2, false>(X, w1, b1, H, nullptr);
  __syncthreads();
  gemm_f32<2, false>(H, w2, b2, A, nullptr);
  __syncthreads();
  if (t < 128) {
    int r = t >> 2, j = t & 3;
    float s = b3[j];
    const float* w = w3 + (j << 8);
    const float* x = A + r * LS;
    #pragma unroll 1
    for (int k = 0; k < 256; k += 4) {
      f32x4 wv = *(const f32x4*)(w + k);
      f32x4 xv = *(const f32x4*)(x + k);
      s += xv[0] * wv[0] + xv[1] * wv[1] + xv[2] * wv[2] + xv[3] * wv[3];
    }
    out[131072 + ((size_t)(row0 + r) << 2) + j] = sigm(s);
  }
}

extern "C" void kernel_launch(void* const* d_in, const int* in_sizes, int n_in,
                              void* d_out, int out_size, void* d_ws, size_t ws_size,
                              hipStream_t stream) {
  const float* gimage = (const float*)d_in[0];
  const int* pts = (const int*)d_in[1];
  const float* gn1w = (const float*)d_in[2];
  const float* gn1b = (const float*)d_in[3];
  const float* c1w = (const float*)d_in[4];
  const float* c1b = (const float*)d_in[5];
  const float* gn2w = (const float*)d_in[6];
  const float* gn2b = (const float*)d_in[7];
  const float* c2w = (const float*)d_in[8];
  const float* c2b = (const float*)d_in[9];
  const float* clsw = (const float*)d_in[10];
  const float* clsb = (const float*)d_in[11];
  const float* w1 = (const float*)d_in[12];
  const float* b1 = (const float*)d_in[13];
  const float* w2 = (const float*)d_in[14];
  const float* b2 = (const float*)d_in[15];
  const float* w3 = (const float*)d_in[16];
  const float* b3 = (const float*)d_in[17];

  if (ws_size >= (size_t)WS_NEED) {
    _Float16* ws = (_Float16*)d_ws;
    prep<<<512, 256, 0, stream>>>(c1w, c2w, w1, w2, ws);
    fused_mfma<<<2048, 256, 0, stream>>>(gimage, pts, gn1w, gn1b, c1b,
                                         gn2w, gn2b, c2b, clsw, clsb,
                                         b1, b2, w3, b3, ws, (float*)d_out);
  } else {
    fused_all<<<2048, 256, 0, stream>>>(gimage, pts, gn1w, gn1b, c1w, c1b,
                                        gn2w, gn2b, c2w, c2b, clsw, clsb,
                                        w1, b1, w2, b2, w3, b3, (float*)d_out);
  }
}